// Round 4
// baseline (465.253 us; speedup 1.0000x reference)
//
#include <hip/hip_runtime.h>
#include <math.h>

namespace {

constexpr int NN  = 50000;
constexpr int CC  = 128;
constexpr int EMn = 1000000;
constexpr int ESn = 200000;

using f32x4  = __attribute__((ext_vector_type(4))) float;
using short8 = __attribute__((ext_vector_type(8))) short;

__device__ __forceinline__ ushort f2bf(float f) {
  unsigned u = __float_as_uint(f);
  return (ushort)((u + 0x7fffu + ((u >> 16) & 1u)) >> 16);   // RNE
}
__device__ __forceinline__ float b2f(ushort u) {
  return __uint_as_float((unsigned)u << 16);
}
__device__ __forceinline__ float softplusf(float x) {
  return (x > 20.f) ? x : log1pf(expf(x));
}

// ---- K0: init scratch ----
__global__ void k_init(int* __restrict__ pidx, float* __restrict__ den,
                       float* __restrict__ num, float* __restrict__ cnt,
                       unsigned* __restrict__ cntd) {
  int i = blockIdx.x * blockDim.x + threadIdx.x;
  if (i < NN) { pidx[i] = -1; den[i] = 0.f; num[i] = 0.f; cnt[i] = 0.f; cntd[i] = 0u; }
}

// ---- K_cvt: bf16 conversion of nodes/nbrs rows + invn (fused norm). 16 lanes/row ----
__global__ void k_cvtnorm(const float* __restrict__ nodes, const float* __restrict__ nbrs,
                          ushort* __restrict__ nodesb, ushort* __restrict__ nbrsb,
                          float* __restrict__ invn) {
  int row = blockIdx.x * 16 + (threadIdx.x >> 4);
  int li = threadIdx.x & 15;
  if (row >= 2 * NN) return;
  bool isn = row < NN;
  const float* src = isn ? nodes + (size_t)row * CC : nbrs + (size_t)(row - NN) * CC;
  ushort* dst      = isn ? nodesb + (size_t)row * CC : nbrsb + (size_t)(row - NN) * CC;
  float4 x0 = *(const float4*)(src + li * 8);
  float4 x1 = *(const float4*)(src + li * 8 + 4);
  short8 v;
  v[0] = (short)f2bf(x0.x); v[1] = (short)f2bf(x0.y);
  v[2] = (short)f2bf(x0.z); v[3] = (short)f2bf(x0.w);
  v[4] = (short)f2bf(x1.x); v[5] = (short)f2bf(x1.y);
  v[6] = (short)f2bf(x1.z); v[7] = (short)f2bf(x1.w);
  *(short8*)(dst + li * 8) = v;
  if (isn) {
    float sq = x0.x * x0.x + x0.y * x0.y + x0.z * x0.z + x0.w * x0.w
             + x1.x * x1.x + x1.y * x1.y + x1.z * x1.z + x1.w * x1.w;
#pragma unroll
    for (int off = 1; off < 16; off <<= 1) sq += __shfl_xor(sq, off, 64);
    if (li == 0) invn[row] = 1.0f / fmaxf(sqrtf(sq), 1e-8f);
  }
}

// ---- K2: partner_index scatter-max ----
__global__ void k_partner(const int* __restrict__ ss, const int* __restrict__ sd,
                          int* __restrict__ pidx) {
  int i = blockIdx.x * blockDim.x + threadIdx.x;
  if (i >= 2 * ESn) return;
  int partner = (i < ESn) ? sd[i] : ss[i - ESn];
  atomicMax(&pidx[partner], i);
}

// ---- K_hist: bucket counts by msg_dst ----
__global__ void k_hist(const int* __restrict__ md, unsigned* __restrict__ cntd) {
  int e = blockIdx.x * blockDim.x + threadIdx.x;
  if (e >= EMn) return;
  atomicAdd(&cntd[md[e]], 1u);
}

// ---- K_scan: single-block exclusive scan over 50000 bucket counts ----
__global__ __launch_bounds__(1024) void k_scan(const unsigned* __restrict__ cntd,
                                               unsigned* __restrict__ offset,
                                               unsigned* __restrict__ cursor) {
  __shared__ unsigned part[1024];
  const int t = threadIdx.x;
  const int CH = 49;                        // 49*1024 >= 50000
  int b = t * CH, e = min(b + CH, NN);
  unsigned loc = 0;
  for (int i = b; i < e; i++) loc += cntd[i];
  part[t] = loc;
  __syncthreads();
#pragma unroll
  for (int off = 1; off < 1024; off <<= 1) {
    unsigned v = (t >= off) ? part[t - off] : 0u;
    __syncthreads();
    part[t] += v;
    __syncthreads();
  }
  unsigned run = part[t] - loc;             // exclusive base
  for (int i = b; i < e; i++) {
    offset[i] = run; cursor[i] = run;
    run += cntd[i];
  }
}

// ---- K_scatter: sorted_src[pos] = msg_src, bucketed by msg_dst ----
__global__ void k_scatter(const int* __restrict__ ms, const int* __restrict__ md,
                          unsigned* __restrict__ cursor, int* __restrict__ sorted_src) {
  int e = blockIdx.x * blockDim.x + threadIdx.x;
  if (e >= EMn) return;
  unsigned pos = atomicAdd(&cursor[md[e]], 1u);
  sorted_src[pos] = ms[e];
}

// ---- K_bucket: one wave per msg_dst bucket; q-row loaded once; 4 edges in flight ----
__global__ void k_bucket(const ushort* __restrict__ nodesb, const float* __restrict__ invn,
                         const int* __restrict__ ss, const int* __restrict__ sd,
                         const int* __restrict__ pidx, const unsigned* __restrict__ offset,
                         const unsigned* __restrict__ cntd, const int* __restrict__ sorted_src,
                         float* __restrict__ den, float* __restrict__ num,
                         float* __restrict__ cnt) {
  int t = threadIdx.x;
  int d = blockIdx.x * 4 + (t >> 6);        // bucket id = wave id
  if (d >= NN) return;
  int n = (int)cntd[d];
  if (n == 0) return;
  int pi = pidx[d];
  if (pi < 0) return;
  int q = (pi < ESn) ? ss[pi] : sd[pi - ESn];
  int l = t & 63, g = l >> 4, li = l & 15;
  short8 xq = *(const short8*)(nodesb + (size_t)q * CC + li * 8);
  float fq[8];
#pragma unroll
  for (int j = 0; j < 8; j++) fq[j] = b2f((ushort)xq[j]);
  float invq = invn[q];
  int base = (int)offset[d];
  float dsum = 0.f, nsum = 0.f;
  for (int i0 = g; i0 < n; i0 += 4) {
    int s = sorted_src[base + i0];
    short8 ys = *(const short8*)(nodesb + (size_t)s * CC + li * 8);
    float dot = 0.f;
#pragma unroll
    for (int j = 0; j < 8; j++) dot += fq[j] * b2f((ushort)ys[j]);
#pragma unroll
    for (int off = 1; off < 16; off <<= 1) dot += __shfl_xor(dot, off, 64);
    float cv = dot * invq * invn[s];
    float wv = expf(10.0f * cv);            // softmax shift-invariant: no max pass
    dsum += wv; nsum += wv * cv;
  }
  // combine the 4 group-partials (each group's lanes hold identical values)
  dsum += __shfl_xor(dsum, 16, 64); dsum += __shfl_xor(dsum, 32, 64);
  nsum += __shfl_xor(nsum, 16, 64); nsum += __shfl_xor(nsum, 32, 64);
  if (l == 0) {
    atomicAdd(&den[q], dsum);
    atomicAdd(&num[q], nsum);
    atomicAdd(&cnt[q], (float)n);
  }
}

// ---- K5: cong_node ----
__global__ void k_cong(const float* __restrict__ den, const float* __restrict__ num,
                       const float* __restrict__ cnt, float* __restrict__ cong) {
  int n = blockIdx.x * blockDim.x + threadIdx.x;
  if (n >= NN) return;
  float c = cnt[n];
  cong[n] = (c > 0.f) ? (num[n] / den[n]) / c : 0.f;
}

// ---- K_prep: transpose + bf16-convert W0 [256x256] and W1 [256x128] ----
__global__ void k_prep(const float* __restrict__ W0, const float* __restrict__ W1,
                       ushort* __restrict__ w0t, ushort* __restrict__ w1t) {
  __shared__ float tl[32][33];
  int b = blockIdx.x;
  const float* src; ushort* dst; int N, tk, tn;
  if (b < 64) { src = W0; dst = w0t; N = 256; tk = b >> 3; tn = b & 7; }
  else        { b -= 64; src = W1; dst = w1t; N = 128; tk = b >> 2; tn = b & 3; }
  int tx = threadIdx.x & 31, ty = threadIdx.x >> 5;
#pragma unroll
  for (int yy = 0; yy < 32; yy += 8)
    tl[ty + yy][tx] = src[(size_t)(tk * 32 + ty + yy) * N + tn * 32 + tx];
  __syncthreads();
#pragma unroll
  for (int yy = 0; yy < 32; yy += 8)
    dst[(size_t)(tn * 32 + ty + yy) * 256 + tk * 32 + tx] = f2bf(tl[tx][ty + yy]);
}

// ---- K6: fused MFMA MLP + heads. 64 edges/block, col-split across 4 waves ----
__global__ __launch_bounds__(256) void k_mlp(
    const ushort* __restrict__ nodesb, const ushort* __restrict__ nbrsb,
    const int* __restrict__ ssrc, const int* __restrict__ sdst,
    const float* __restrict__ cong,
    const ushort* __restrict__ w0t, const ushort* __restrict__ w1t,
    const float* __restrict__ b0, const float* __restrict__ g0, const float* __restrict__ be0,
    const float* __restrict__ b1, const float* __restrict__ g1, const float* __restrict__ be1,
    const float* __restrict__ Wp, const float* __restrict__ bp,
    const float* __restrict__ Ww, const float* __restrict__ bw,
    const float* __restrict__ sscale, const float* __restrict__ sshift,
    const float* __restrict__ craw, float* __restrict__ out) {
  __shared__ ushort tile[64][256];          // combined (bf16, XOR-swizzled), reused for h_ln
  __shared__ float pstat[4][64][2];         // per-wave (s, sq) partials; reused for (pd, ws)
  __shared__ float mustd[64][2];
  __shared__ float nsimb[64];
  __shared__ int   eidx[64][2];

  const int t = threadIdx.x;
  const int w = t >> 6, l = t & 63;
  const int li = l & 15, hi = l >> 4;
  const int s0 = blockIdx.x * 64;

  if (t < 64) { eidx[t][0] = ssrc[s0 + t]; eidx[t][1] = sdst[s0 + t]; }

  // ---- stage combined = [a | m] bf16, swizzled; wave stages its 16 rows ----
  {
    int r = w * 16 + (l >> 2), q = l & 3;
    int es = ssrc[s0 + r], ed = sdst[s0 + r];
    const short8* xs = (const short8*)(nodesb + (size_t)es * CC + q * 32);
    const short8* ys = (const short8*)(nodesb + (size_t)ed * CC + q * 32);
    int sw = (r & 7) << 3;
#pragma unroll
    for (int i = 0; i < 4; i++) {
      short8 x = xs[i], y = ys[i];
      short8 av, mv;
#pragma unroll
      for (int j = 0; j < 8; j++) {
        float fx = b2f((ushort)x[j]), fy = b2f((ushort)y[j]);
        av[j] = (short)f2bf(fx + fy);
        mv[j] = (short)f2bf(fx * fy);
      }
      *(short8*)&tile[r][(q * 32 + i * 8) ^ sw] = av;
      *(short8*)&tile[r][(128 + q * 32 + i * 8) ^ sw] = mv;
    }
  }
  __syncthreads();                          // B1

  const int swl = (li & 7) << 3;
  const int n0 = w * 64;                    // GEMM1 col base for this wave

  // ---- GEMM1: h cols [n0, n0+64) for all 64 edges ----
  f32x4 acc[4][4];                          // [nf][ef]
#pragma unroll
  for (int nf = 0; nf < 4; nf++) {
    float bv = b0[n0 + nf * 16 + li];
#pragma unroll
    for (int ef = 0; ef < 4; ef++) acc[nf][ef] = {bv, bv, bv, bv};
  }
#pragma unroll
  for (int kk = 0; kk < 8; kk++) {
    short8 a[4], b[4];
#pragma unroll
    for (int ef = 0; ef < 4; ef++)
      a[ef] = *(const short8*)&tile[ef * 16 + li][(kk * 32 + hi * 8) ^ swl];
#pragma unroll
    for (int nf = 0; nf < 4; nf++)
      b[nf] = *(const short8*)(w0t + (size_t)(n0 + nf * 16 + li) * 256 + kk * 32 + hi * 8);
#pragma unroll
    for (int nf = 0; nf < 4; nf++)
#pragma unroll
      for (int ef = 0; ef < 4; ef++)
        acc[nf][ef] = __builtin_amdgcn_mfma_f32_16x16x32_bf16(a[ef], b[nf], acc[nf][ef], 0, 0, 0);
  }

  // ---- LN1 partials ----
  {
    f32x4 ps[4], qs[4];
#pragma unroll
    for (int ef = 0; ef < 4; ef++) {
      f32x4 s = acc[0][ef] + acc[1][ef] + acc[2][ef] + acc[3][ef];
      f32x4 q = acc[0][ef] * acc[0][ef] + acc[1][ef] * acc[1][ef]
              + acc[2][ef] * acc[2][ef] + acc[3][ef] * acc[3][ef];
      ps[ef] = s; qs[ef] = q;
    }
#pragma unroll
    for (int ef = 0; ef < 4; ef++)
#pragma unroll
      for (int j = 0; j < 4; j++)
#pragma unroll
        for (int off = 1; off < 16; off <<= 1) {
          ps[ef][j] += __shfl_xor(ps[ef][j], off, 64);
          qs[ef][j] += __shfl_xor(qs[ef][j], off, 64);
        }
    if (li < 4) {
#pragma unroll
      for (int ef = 0; ef < 4; ef++) {
        int r = ef * 16 + hi * 4 + li;
        pstat[w][r][0] = ps[ef][li];
        pstat[w][r][1] = qs[ef][li];
      }
    }
  }
  __syncthreads();                          // B2
  if (t < 64) {
    float s = 0.f, sq = 0.f;
#pragma unroll
    for (int ww = 0; ww < 4; ww++) { s += pstat[ww][t][0]; sq += pstat[ww][t][1]; }
    float mu = s * (1.f / 256.f);
    float var = sq * (1.f / 256.f) - mu * mu;
    mustd[t][0] = mu; mustd[t][1] = rsqrtf(var + 1e-5f);
  }

  // ---- nbrs similarity (edge-split: wave w -> edges [16w,16w+16), 4 lanes/edge) ----
  {
    int e = w * 16 + (l >> 2), q4 = l & 3;
    int es = eidx[e][0], ed = eidx[e][1];
    const short8* xs = (const short8*)(nbrsb + (size_t)es * CC + q4 * 32);
    const short8* ys = (const short8*)(nbrsb + (size_t)ed * CC + q4 * 32);
    float dd = 0.f;
#pragma unroll
    for (int i = 0; i < 4; i++) {
      short8 x = xs[i], y = ys[i];
#pragma unroll
      for (int j = 0; j < 8; j++) dd += b2f((ushort)x[j]) * b2f((ushort)y[j]);
    }
    dd += __shfl_xor(dd, 1, 64);
    dd += __shfl_xor(dd, 2, 64);
    if (q4 == 0) nsimb[e] = dd;
  }
  __syncthreads();                          // B3

  // ---- LN1 normalize + relu -> tile (h_ln) ----
  {
    float mu[4][4], rs[4][4];
#pragma unroll
    for (int ef = 0; ef < 4; ef++)
#pragma unroll
      for (int j = 0; j < 4; j++) {
        int r = ef * 16 + hi * 4 + j;
        mu[ef][j] = mustd[r][0]; rs[ef][j] = mustd[r][1];
      }
#pragma unroll
    for (int nf = 0; nf < 4; nf++) {
      int col = n0 + nf * 16 + li;
      float gv = g0[col], bev = be0[col];
#pragma unroll
      for (int ef = 0; ef < 4; ef++)
#pragma unroll
        for (int j = 0; j < 4; j++) {
          int r = ef * 16 + hi * 4 + j;
          float v = fmaxf((acc[nf][ef][j] - mu[ef][j]) * rs[ef][j] * gv + bev, 0.f);
          tile[r][col ^ ((r & 7) << 3)] = f2bf(v);
        }
    }
  }
  __syncthreads();                          // B4

  // ---- GEMM2: ef cols [32w, 32w+32) for all 64 edges ----
  const int n2 = w * 32;
  f32x4 acc2[2][4];
#pragma unroll
  for (int nf = 0; nf < 2; nf++) {
    float bv = b1[n2 + nf * 16 + li];
#pragma unroll
    for (int ef = 0; ef < 4; ef++) acc2[nf][ef] = {bv, bv, bv, bv};
  }
#pragma unroll
  for (int kk = 0; kk < 8; kk++) {
    short8 a[4], b[2];
#pragma unroll
    for (int ef = 0; ef < 4; ef++)
      a[ef] = *(const short8*)&tile[ef * 16 + li][(kk * 32 + hi * 8) ^ swl];
#pragma unroll
    for (int nf = 0; nf < 2; nf++)
      b[nf] = *(const short8*)(w1t + (size_t)(n2 + nf * 16 + li) * 256 + kk * 32 + hi * 8);
#pragma unroll
    for (int nf = 0; nf < 2; nf++)
#pragma unroll
      for (int ef = 0; ef < 4; ef++)
        acc2[nf][ef] = __builtin_amdgcn_mfma_f32_16x16x32_bf16(a[ef], b[nf], acc2[nf][ef], 0, 0, 0);
  }

  // ---- LN2 partials ----
  {
    f32x4 ps[4], qs[4];
#pragma unroll
    for (int ef = 0; ef < 4; ef++) {
      ps[ef] = acc2[0][ef] + acc2[1][ef];
      qs[ef] = acc2[0][ef] * acc2[0][ef] + acc2[1][ef] * acc2[1][ef];
    }
#pragma unroll
    for (int ef = 0; ef < 4; ef++)
#pragma unroll
      for (int j = 0; j < 4; j++)
#pragma unroll
        for (int off = 1; off < 16; off <<= 1) {
          ps[ef][j] += __shfl_xor(ps[ef][j], off, 64);
          qs[ef][j] += __shfl_xor(qs[ef][j], off, 64);
        }
    if (li < 4) {
#pragma unroll
      for (int ef = 0; ef < 4; ef++) {
        int r = ef * 16 + hi * 4 + li;
        pstat[w][r][0] = ps[ef][li];
        pstat[w][r][1] = qs[ef][li];
      }
    }
  }
  __syncthreads();                          // B5
  if (t < 64) {
    float s = 0.f, sq = 0.f;
#pragma unroll
    for (int ww = 0; ww < 4; ww++) { s += pstat[ww][t][0]; sq += pstat[ww][t][1]; }
    float mu = s * (1.f / 128.f);
    float var = sq * (1.f / 128.f) - mu * mu;
    mustd[t][0] = mu; mustd[t][1] = rsqrtf(var + 1e-5f);
  }
  __syncthreads();                          // B6

  // ---- LN2 normalize + relu + head partial dots ----
  {
    float mu[4][4], rs[4][4];
#pragma unroll
    for (int ef = 0; ef < 4; ef++)
#pragma unroll
      for (int j = 0; j < 4; j++) {
        int r = ef * 16 + hi * 4 + j;
        mu[ef][j] = mustd[r][0]; rs[ef][j] = mustd[r][1];
      }
    f32x4 pdp[4] = {{0,0,0,0},{0,0,0,0},{0,0,0,0},{0,0,0,0}};
    f32x4 wsp[4] = {{0,0,0,0},{0,0,0,0},{0,0,0,0},{0,0,0,0}};
#pragma unroll
    for (int nf = 0; nf < 2; nf++) {
      int col = n2 + nf * 16 + li;
      float gv = g1[col], bev = be1[col];
      float wpv = Wp[col], wwv = Ww[col];
#pragma unroll
      for (int ef = 0; ef < 4; ef++)
#pragma unroll
        for (int j = 0; j < 4; j++) {
          float e = fmaxf((acc2[nf][ef][j] - mu[ef][j]) * rs[ef][j] * gv + bev, 0.f);
          pdp[ef][j] += e * wpv;
          wsp[ef][j] += e * wwv;
        }
    }
#pragma unroll
    for (int ef = 0; ef < 4; ef++)
#pragma unroll
      for (int j = 0; j < 4; j++)
#pragma unroll
        for (int off = 1; off < 16; off <<= 1) {
          pdp[ef][j] += __shfl_xor(pdp[ef][j], off, 64);
          wsp[ef][j] += __shfl_xor(wsp[ef][j], off, 64);
        }
    if (li < 4) {
#pragma unroll
      for (int ef = 0; ef < 4; ef++) {
        int r = ef * 16 + hi * 4 + li;
        pstat[w][r][0] = pdp[ef][li];
        pstat[w][r][1] = wsp[ef][li];
      }
    }
  }
  __syncthreads();                          // B7

  if (t < 64) {
    float pd = 0.f, ws = 0.f;
#pragma unroll
    for (int ww = 0; ww < 4; ww++) { pd += pstat[ww][t][0]; ws += pstat[ww][t][1]; }
    float nsim = nsimb[t];
    int es = eidx[t][0], ed = eidx[t][1];
    float u0 = softplusf(craw[0]), u1 = softplusf(craw[1]), u2 = softplusf(craw[2]);
    float usum = u0 + u1 + u2;
    float c0 = u0 / usum, c1 = u1 / usum, c2 = u2 / usum;
    float sc = sscale[0], sh = sshift[0];
    int sidx = s0 + t;
    out[3 * sidx + 0] = c0 * (pd + bp[0]);
    out[3 * sidx + 1] = c1 * (sc * (nsim + sh));
    out[3 * sidx + 2] = c2 * (sc * (cong[es] + cong[ed] + sh));
    out[3 * ESn + sidx] = fmaxf(ws + nsim * Ww[128] + bw[0], 0.f);
    if (blockIdx.x == 0 && t == 0) {
      out[4 * ESn + 0] = c0; out[4 * ESn + 1] = c1; out[4 * ESn + 2] = c2;
    }
  }
}

} // namespace

extern "C" void kernel_launch(void* const* d_in, const int* in_sizes, int n_in,
                              void* d_out, int out_size, void* d_ws, size_t ws_size,
                              hipStream_t stream) {
  (void)in_sizes; (void)n_in; (void)out_size; (void)ws_size;
  const float* nodes  = (const float*)d_in[0];
  const float* nbrs   = (const float*)d_in[1];
  const int* sup_src  = (const int*)d_in[2];
  const int* sup_dst  = (const int*)d_in[3];
  const int* msg_src  = (const int*)d_in[4];
  const int* msg_dst  = (const int*)d_in[5];
  // d_in[6] message_edgestr: dead
  const float* W0  = (const float*)d_in[7];
  const float* b0  = (const float*)d_in[8];
  const float* g0  = (const float*)d_in[9];
  const float* be0 = (const float*)d_in[10];
  const float* W1  = (const float*)d_in[11];
  const float* b1  = (const float*)d_in[12];
  const float* g1  = (const float*)d_in[13];
  const float* be1 = (const float*)d_in[14];
  const float* Wp  = (const float*)d_in[15];
  const float* bp  = (const float*)d_in[16];
  const float* Ww  = (const float*)d_in[17];
  const float* bw  = (const float*)d_in[18];
  const float* sscale = (const float*)d_in[19];
  const float* sshift = (const float*)d_in[20];
  const float* craw   = (const float*)d_in[21];
  // d_in[22..27] mm_*: dead
  float* out = (float*)d_out;

  char* p = (char*)d_ws;
  auto take = [&](size_t bytes) -> char* {
    char* r = p; p += (bytes + 255) & ~(size_t)255; return r;
  };
  ushort*   w0t    = (ushort*)take((size_t)256 * 256 * 2);
  ushort*   w1t    = (ushort*)take((size_t)128 * 256 * 2);
  ushort*   nodesb = (ushort*)take((size_t)NN * CC * 2);
  ushort*   nbrsb  = (ushort*)take((size_t)NN * CC * 2);
  float*    invn   = (float*)take((size_t)NN * 4);
  int*      pidx   = (int*)take((size_t)NN * 4);
  float*    den    = (float*)take((size_t)NN * 4);
  float*    num    = (float*)take((size_t)NN * 4);
  float*    cnt    = (float*)take((size_t)NN * 4);
  float*    cong   = (float*)take((size_t)NN * 4);
  unsigned* cntd   = (unsigned*)take((size_t)NN * 4);
  unsigned* offs   = (unsigned*)take((size_t)NN * 4);
  unsigned* cursor = (unsigned*)take((size_t)NN * 4);
  int*      ssrc   = (int*)take((size_t)EMn * 4);

  k_init<<<(NN + 255) / 256, 256, 0, stream>>>(pidx, den, num, cnt, cntd);
  k_cvtnorm<<<(2 * NN + 15) / 16, 256, 0, stream>>>(nodes, nbrs, nodesb, nbrsb, invn);
  k_prep<<<96, 256, 0, stream>>>(W0, W1, w0t, w1t);
  k_partner<<<(2 * ESn + 255) / 256, 256, 0, stream>>>(sup_src, sup_dst, pidx);
  k_hist<<<(EMn + 255) / 256, 256, 0, stream>>>(msg_dst, cntd);
  k_scan<<<1, 1024, 0, stream>>>(cntd, offs, cursor);
  k_scatter<<<(EMn + 255) / 256, 256, 0, stream>>>(msg_src, msg_dst, cursor, ssrc);
  k_bucket<<<(NN + 3) / 4, 256, 0, stream>>>(nodesb, invn, sup_src, sup_dst, pidx,
                                             offs, cntd, ssrc, den, num, cnt);
  k_cong<<<(NN + 255) / 256, 256, 0, stream>>>(den, num, cnt, cong);
  k_mlp<<<ESn / 64, 256, 0, stream>>>(nodesb, nbrsb, sup_src, sup_dst, cong,
                                      w0t, w1t, b0, g0, be0, b1, g1, be1,
                                      Wp, bp, Ww, bw, sscale, sshift, craw, out);
}

// Round 5
// 348.571 us; speedup vs baseline: 1.3347x; 1.3347x over previous
//
#include <hip/hip_runtime.h>
#include <math.h>

namespace {

constexpr int NN  = 50000;
constexpr int CC  = 128;
constexpr int EMn = 1000000;
constexpr int ESn = 200000;

using f32x4  = __attribute__((ext_vector_type(4))) float;
using short8 = __attribute__((ext_vector_type(8))) short;

__device__ __forceinline__ ushort f2bf(float f) {
  unsigned u = __float_as_uint(f);
  return (ushort)((u + 0x7fffu + ((u >> 16) & 1u)) >> 16);   // RNE
}
__device__ __forceinline__ float softplusf(float x) {
  return (x > 20.f) ? x : log1pf(expf(x));
}
__device__ __forceinline__ int sdot4i(unsigned a, unsigned b, int c) {
#if __has_builtin(__builtin_amdgcn_sdot4)
  return __builtin_amdgcn_sdot4((int)a, (int)b, c, false);
#else
  int r = c;
#pragma unroll
  for (int k = 0; k < 4; k++) {
    int xa = ((int)(a << (24 - 8 * k))) >> 24;
    int xb = ((int)(b << (24 - 8 * k))) >> 24;
    r += xa * xb;
  }
  return r;
#endif
}
__device__ __forceinline__ unsigned pack4(float a, float b, float c, float d) {
  int ia = __float2int_rn(a), ib = __float2int_rn(b);
  int ic = __float2int_rn(c), id = __float2int_rn(d);
  return (unsigned)(ia & 255) | ((unsigned)(ib & 255) << 8) |
         ((unsigned)(ic & 255) << 16) | ((unsigned)(id & 255) << 24);
}

// ---- K0: init scratch ----
__global__ void k_init(int* __restrict__ pidx, float* __restrict__ den,
                       float* __restrict__ num, float* __restrict__ cnt) {
  int i = blockIdx.x * blockDim.x + threadIdx.x;
  if (i < NN) { pidx[i] = -1; den[i] = 0.f; num[i] = 0.f; cnt[i] = 0.f; }
}

// ---- K_cvtq: per-row int8 quantization. nodes -> qnodes(+nscale)+qunit; nbrs -> qnbrs(+nbscale) ----
__global__ void k_cvtq(const float* __restrict__ nodes, const float* __restrict__ nbrs,
                       char* __restrict__ qnodes, char* __restrict__ qunit,
                       char* __restrict__ qnbrs, float* __restrict__ nscale,
                       float* __restrict__ nbscale) {
  int row = blockIdx.x * 16 + (threadIdx.x >> 4);
  int li = threadIdx.x & 15;
  if (row >= 2 * NN) return;
  bool isn = row < NN;
  int r = isn ? row : row - NN;
  const float* src = (isn ? nodes : nbrs) + (size_t)r * CC;
  float4 x0 = *(const float4*)(src + li * 8);
  float4 x1 = *(const float4*)(src + li * 8 + 4);
  float v[8] = {x0.x, x0.y, x0.z, x0.w, x1.x, x1.y, x1.z, x1.w};
  float amax = 0.f, sq = 0.f;
#pragma unroll
  for (int j = 0; j < 8; j++) { amax = fmaxf(amax, fabsf(v[j])); sq += v[j] * v[j]; }
#pragma unroll
  for (int off = 1; off < 16; off <<= 1) {
    amax = fmaxf(amax, __shfl_xor(amax, off, 64));
    sq += __shfl_xor(sq, off, 64);
  }
  amax = fmaxf(amax, 1e-8f);
  float rs = 127.f / amax;
  uint2 p;
  p.x = pack4(v[0] * rs, v[1] * rs, v[2] * rs, v[3] * rs);
  p.y = pack4(v[4] * rs, v[5] * rs, v[6] * rs, v[7] * rs);
  if (isn) {
    *(uint2*)(qnodes + (size_t)r * CC + li * 8) = p;
    float ru = 127.f / fmaxf(sqrtf(sq), 1e-8f);
    uint2 pu;
    pu.x = pack4(v[0] * ru, v[1] * ru, v[2] * ru, v[3] * ru);
    pu.y = pack4(v[4] * ru, v[5] * ru, v[6] * ru, v[7] * ru);
    *(uint2*)(qunit + (size_t)r * CC + li * 8) = pu;
    if (li == 0) nscale[r] = amax / 127.f;
  } else {
    *(uint2*)(qnbrs + (size_t)r * CC + li * 8) = p;
    if (li == 0) nbscale[r] = amax / 127.f;
  }
}

// ---- K2: partner_index scatter-max ----
__global__ void k_partner(const int* __restrict__ ss, const int* __restrict__ sd,
                          int* __restrict__ pidx) {
  int i = blockIdx.x * blockDim.x + threadIdx.x;
  if (i >= 2 * ESn) return;
  int partner = (i < ESn) ? sd[i] : ss[i - ESn];
  atomicMax(&pidx[partner], i);
}

// ---- K3: fused cos + segmented sums. 8 lanes/edge, int8 unit rows (128 B/gather) ----
__global__ void k_cos8(const char* __restrict__ qunit,
                       const int* __restrict__ ss, const int* __restrict__ sd,
                       const int* __restrict__ ms, const int* __restrict__ md,
                       const int* __restrict__ pidx, float* __restrict__ den,
                       float* __restrict__ num, float* __restrict__ cnt) {
  int t = threadIdx.x;
  int e = blockIdx.x * 32 + (t >> 3);
  int li = t & 7;
  int d = md[e];
  int pi = pidx[d];
  if (pi < 0) return;                       // uniform per 8-lane group
  int q = (pi < ESn) ? ss[pi] : sd[pi - ESn];
  int s = ms[e];
  uint4 a = ((const uint4*)(qunit + (size_t)q * CC))[li];
  uint4 b = ((const uint4*)(qunit + (size_t)s * CC))[li];
  int acc = 0;
  acc = sdot4i(a.x, b.x, acc); acc = sdot4i(a.y, b.y, acc);
  acc = sdot4i(a.z, b.z, acc); acc = sdot4i(a.w, b.w, acc);
#pragma unroll
  for (int off = 1; off < 8; off <<= 1) acc += __shfl_xor(acc, off, 64);
  if (li == 0) {
    float cv = (float)acc * (1.0f / (127.f * 127.f));
    float wv = expf(10.0f * cv);            // softmax shift-invariant: no max pass
    atomicAdd(&den[q], wv);
    atomicAdd(&num[q], wv * cv);
    atomicAdd(&cnt[q], 1.0f);
  }
}

// ---- K5: cong_node ----
__global__ void k_cong(const float* __restrict__ den, const float* __restrict__ num,
                       const float* __restrict__ cnt, float* __restrict__ cong) {
  int n = blockIdx.x * blockDim.x + threadIdx.x;
  if (n >= NN) return;
  float c = cnt[n];
  cong[n] = (c > 0.f) ? (num[n] / den[n]) / c : 0.f;
}

// ---- K_prep: transpose + bf16-convert W0 [256x256] and W1 [256x128] ----
__global__ void k_prep(const float* __restrict__ W0, const float* __restrict__ W1,
                       ushort* __restrict__ w0t, ushort* __restrict__ w1t) {
  __shared__ float tl[32][33];
  int b = blockIdx.x;
  const float* src; ushort* dst; int N, tk, tn;
  if (b < 64) { src = W0; dst = w0t; N = 256; tk = b >> 3; tn = b & 7; }
  else        { b -= 64; src = W1; dst = w1t; N = 128; tk = b >> 2; tn = b & 3; }
  int tx = threadIdx.x & 31, ty = threadIdx.x >> 5;
#pragma unroll
  for (int yy = 0; yy < 32; yy += 8)
    tl[ty + yy][tx] = src[(size_t)(tk * 32 + ty + yy) * N + tn * 32 + tx];
  __syncthreads();
#pragma unroll
  for (int yy = 0; yy < 32; yy += 8)
    dst[(size_t)(tn * 32 + ty + yy) * 256 + tk * 32 + tx] = f2bf(tl[tx][ty + yy]);
}

// ---- K6: fused MFMA MLP + heads. 64 edges/block, col-split across 4 waves, int8 gathers ----
__global__ __launch_bounds__(256) void k_mlp(
    const char* __restrict__ qnodes, const float* __restrict__ nscale,
    const char* __restrict__ qnbrs, const float* __restrict__ nbscale,
    const int* __restrict__ ssrc, const int* __restrict__ sdst,
    const float* __restrict__ cong,
    const ushort* __restrict__ w0t, const ushort* __restrict__ w1t,
    const float* __restrict__ b0, const float* __restrict__ g0, const float* __restrict__ be0,
    const float* __restrict__ b1, const float* __restrict__ g1, const float* __restrict__ be1,
    const float* __restrict__ Wp, const float* __restrict__ bp,
    const float* __restrict__ Ww, const float* __restrict__ bw,
    const float* __restrict__ sscale, const float* __restrict__ sshift,
    const float* __restrict__ craw, float* __restrict__ out) {
  __shared__ ushort tile[64][256];          // combined (bf16, XOR-swizzled), reused for h_ln
  __shared__ float pstat[4][64][2];         // per-wave (s, sq) partials; reused for (pd, ws)
  __shared__ float mustd[64][2];
  __shared__ float nsimb[64];
  __shared__ int   eidx[64][2];

  const int t = threadIdx.x;
  const int w = t >> 6, l = t & 63;
  const int li = l & 15, hi = l >> 4;
  const int s0 = blockIdx.x * 64;

  if (t < 64) { eidx[t][0] = ssrc[s0 + t]; eidx[t][1] = sdst[s0 + t]; }

  // ---- stage combined = [a | m] bf16 from int8 rows; 4 lanes/row, 32 elems/lane ----
  {
    int r = w * 16 + (l >> 2), q4 = l & 3;
    int es = ssrc[s0 + r], ed = sdst[s0 + r];
    float sxs = nscale[es], sxd = nscale[ed];
    const uint4* xs = (const uint4*)(qnodes + (size_t)es * CC) + q4 * 2;
    const uint4* ys = (const uint4*)(qnodes + (size_t)ed * CC) + q4 * 2;
    int sw = (r & 7) << 3;
#pragma unroll
    for (int i = 0; i < 2; i++) {
      uint4 xu = xs[i], yu = ys[i];
      unsigned xd[4] = {xu.x, xu.y, xu.z, xu.w};
      unsigned yd[4] = {yu.x, yu.y, yu.z, yu.w};
#pragma unroll
      for (int c = 0; c < 2; c++) {
        short8 a8, m8;
#pragma unroll
        for (int dk = 0; dk < 8; dk++) {
          int dd = c * 2 + (dk >> 2), k = dk & 3;
          float fx = (float)(((int)(xd[dd] << (24 - 8 * k))) >> 24) * sxs;
          float fy = (float)(((int)(yd[dd] << (24 - 8 * k))) >> 24) * sxd;
          a8[dk] = (short)f2bf(fx + fy);
          m8[dk] = (short)f2bf(fx * fy);
        }
        int base = q4 * 32 + i * 16 + c * 8;
        *(short8*)&tile[r][base ^ sw] = a8;
        *(short8*)&tile[r][(128 + base) ^ sw] = m8;
      }
    }
  }
  __syncthreads();                          // B1

  const int swl = (li & 7) << 3;
  const int n0 = w * 64;                    // GEMM1 col base for this wave

  // ---- GEMM1: h cols [n0, n0+64) for all 64 edges ----
  f32x4 acc[4][4];                          // [nf][ef]
#pragma unroll
  for (int nf = 0; nf < 4; nf++) {
    float bv = b0[n0 + nf * 16 + li];
#pragma unroll
    for (int ef = 0; ef < 4; ef++) acc[nf][ef] = {bv, bv, bv, bv};
  }
#pragma unroll
  for (int kk = 0; kk < 8; kk++) {
    short8 a[4], b[4];
#pragma unroll
    for (int ef = 0; ef < 4; ef++)
      a[ef] = *(const short8*)&tile[ef * 16 + li][(kk * 32 + hi * 8) ^ swl];
#pragma unroll
    for (int nf = 0; nf < 4; nf++)
      b[nf] = *(const short8*)(w0t + (size_t)(n0 + nf * 16 + li) * 256 + kk * 32 + hi * 8);
#pragma unroll
    for (int nf = 0; nf < 4; nf++)
#pragma unroll
      for (int ef = 0; ef < 4; ef++)
        acc[nf][ef] = __builtin_amdgcn_mfma_f32_16x16x32_bf16(a[ef], b[nf], acc[nf][ef], 0, 0, 0);
  }

  // ---- LN1 partials ----
  {
    f32x4 ps[4], qs[4];
#pragma unroll
    for (int ef = 0; ef < 4; ef++) {
      ps[ef] = acc[0][ef] + acc[1][ef] + acc[2][ef] + acc[3][ef];
      qs[ef] = acc[0][ef] * acc[0][ef] + acc[1][ef] * acc[1][ef]
             + acc[2][ef] * acc[2][ef] + acc[3][ef] * acc[3][ef];
    }
#pragma unroll
    for (int ef = 0; ef < 4; ef++)
#pragma unroll
      for (int j = 0; j < 4; j++)
#pragma unroll
        for (int off = 1; off < 16; off <<= 1) {
          ps[ef][j] += __shfl_xor(ps[ef][j], off, 64);
          qs[ef][j] += __shfl_xor(qs[ef][j], off, 64);
        }
    if (li < 4) {
#pragma unroll
      for (int ef = 0; ef < 4; ef++) {
        int r = ef * 16 + hi * 4 + li;
        pstat[w][r][0] = ps[ef][li];
        pstat[w][r][1] = qs[ef][li];
      }
    }
  }
  __syncthreads();                          // B2
  if (t < 64) {
    float s = 0.f, sq = 0.f;
#pragma unroll
    for (int ww = 0; ww < 4; ww++) { s += pstat[ww][t][0]; sq += pstat[ww][t][1]; }
    float mu = s * (1.f / 256.f);
    float var = sq * (1.f / 256.f) - mu * mu;
    mustd[t][0] = mu; mustd[t][1] = rsqrtf(var + 1e-5f);
  }

  // ---- nbrs similarity (int8 dot; wave w -> edges [16w,16w+16), 4 lanes/edge) ----
  {
    int e = w * 16 + (l >> 2), q4 = l & 3;
    int es = eidx[e][0], ed = eidx[e][1];
    const uint4* xs = (const uint4*)(qnbrs + (size_t)es * CC) + q4 * 2;
    const uint4* ys = (const uint4*)(qnbrs + (size_t)ed * CC) + q4 * 2;
    int acc8 = 0;
#pragma unroll
    for (int i = 0; i < 2; i++) {
      uint4 x = xs[i], y = ys[i];
      acc8 = sdot4i(x.x, y.x, acc8); acc8 = sdot4i(x.y, y.y, acc8);
      acc8 = sdot4i(x.z, y.z, acc8); acc8 = sdot4i(x.w, y.w, acc8);
    }
    acc8 += __shfl_xor(acc8, 1, 64);
    acc8 += __shfl_xor(acc8, 2, 64);
    if (q4 == 0) nsimb[e] = (float)acc8 * nbscale[es] * nbscale[ed];
  }
  __syncthreads();                          // B3

  // ---- LN1 normalize + relu -> tile (h_ln) ----
  {
    float mu[4][4], rs[4][4];
#pragma unroll
    for (int ef = 0; ef < 4; ef++)
#pragma unroll
      for (int j = 0; j < 4; j++) {
        int r = ef * 16 + hi * 4 + j;
        mu[ef][j] = mustd[r][0]; rs[ef][j] = mustd[r][1];
      }
#pragma unroll
    for (int nf = 0; nf < 4; nf++) {
      int col = n0 + nf * 16 + li;
      float gv = g0[col], bev = be0[col];
#pragma unroll
      for (int ef = 0; ef < 4; ef++)
#pragma unroll
        for (int j = 0; j < 4; j++) {
          int r = ef * 16 + hi * 4 + j;
          float v = fmaxf((acc[nf][ef][j] - mu[ef][j]) * rs[ef][j] * gv + bev, 0.f);
          tile[r][col ^ ((r & 7) << 3)] = f2bf(v);
        }
    }
  }
  __syncthreads();                          // B4

  // ---- GEMM2: ef cols [32w, 32w+32) for all 64 edges ----
  const int n2 = w * 32;
  f32x4 acc2[2][4];
#pragma unroll
  for (int nf = 0; nf < 2; nf++) {
    float bv = b1[n2 + nf * 16 + li];
#pragma unroll
    for (int ef = 0; ef < 4; ef++) acc2[nf][ef] = {bv, bv, bv, bv};
  }
#pragma unroll
  for (int kk = 0; kk < 8; kk++) {
    short8 a[4], b[2];
#pragma unroll
    for (int ef = 0; ef < 4; ef++)
      a[ef] = *(const short8*)&tile[ef * 16 + li][(kk * 32 + hi * 8) ^ swl];
#pragma unroll
    for (int nf = 0; nf < 2; nf++)
      b[nf] = *(const short8*)(w1t + (size_t)(n2 + nf * 16 + li) * 256 + kk * 32 + hi * 8);
#pragma unroll
    for (int nf = 0; nf < 2; nf++)
#pragma unroll
      for (int ef = 0; ef < 4; ef++)
        acc2[nf][ef] = __builtin_amdgcn_mfma_f32_16x16x32_bf16(a[ef], b[nf], acc2[nf][ef], 0, 0, 0);
  }

  // ---- LN2 partials ----
  {
    f32x4 ps[4], qs[4];
#pragma unroll
    for (int ef = 0; ef < 4; ef++) {
      ps[ef] = acc2[0][ef] + acc2[1][ef];
      qs[ef] = acc2[0][ef] * acc2[0][ef] + acc2[1][ef] * acc2[1][ef];
    }
#pragma unroll
    for (int ef = 0; ef < 4; ef++)
#pragma unroll
      for (int j = 0; j < 4; j++)
#pragma unroll
        for (int off = 1; off < 16; off <<= 1) {
          ps[ef][j] += __shfl_xor(ps[ef][j], off, 64);
          qs[ef][j] += __shfl_xor(qs[ef][j], off, 64);
        }
    if (li < 4) {
#pragma unroll
      for (int ef = 0; ef < 4; ef++) {
        int r = ef * 16 + hi * 4 + li;
        pstat[w][r][0] = ps[ef][li];
        pstat[w][r][1] = qs[ef][li];
      }
    }
  }
  __syncthreads();                          // B5
  if (t < 64) {
    float s = 0.f, sq = 0.f;
#pragma unroll
    for (int ww = 0; ww < 4; ww++) { s += pstat[ww][t][0]; sq += pstat[ww][t][1]; }
    float mu = s * (1.f / 128.f);
    float var = sq * (1.f / 128.f) - mu * mu;
    mustd[t][0] = mu; mustd[t][1] = rsqrtf(var + 1e-5f);
  }
  __syncthreads();                          // B6

  // ---- LN2 normalize + relu + head partial dots ----
  {
    float mu[4][4], rs[4][4];
#pragma unroll
    for (int ef = 0; ef < 4; ef++)
#pragma unroll
      for (int j = 0; j < 4; j++) {
        int r = ef * 16 + hi * 4 + j;
        mu[ef][j] = mustd[r][0]; rs[ef][j] = mustd[r][1];
      }
    f32x4 pdp[4] = {{0,0,0,0},{0,0,0,0},{0,0,0,0},{0,0,0,0}};
    f32x4 wsp[4] = {{0,0,0,0},{0,0,0,0},{0,0,0,0},{0,0,0,0}};
#pragma unroll
    for (int nf = 0; nf < 2; nf++) {
      int col = n2 + nf * 16 + li;
      float gv = g1[col], bev = be1[col];
      float wpv = Wp[col], wwv = Ww[col];
#pragma unroll
      for (int ef = 0; ef < 4; ef++)
#pragma unroll
        for (int j = 0; j < 4; j++) {
          float e = fmaxf((acc2[nf][ef][j] - mu[ef][j]) * rs[ef][j] * gv + bev, 0.f);
          pdp[ef][j] += e * wpv;
          wsp[ef][j] += e * wwv;
        }
    }
#pragma unroll
    for (int ef = 0; ef < 4; ef++)
#pragma unroll
      for (int j = 0; j < 4; j++)
#pragma unroll
        for (int off = 1; off < 16; off <<= 1) {
          pdp[ef][j] += __shfl_xor(pdp[ef][j], off, 64);
          wsp[ef][j] += __shfl_xor(wsp[ef][j], off, 64);
        }
    if (li < 4) {
#pragma unroll
      for (int ef = 0; ef < 4; ef++) {
        int r = ef * 16 + hi * 4 + li;
        pstat[w][r][0] = pdp[ef][li];
        pstat[w][r][1] = wsp[ef][li];
      }
    }
  }
  __syncthreads();                          // B7

  if (t < 64) {
    float pd = 0.f, ws = 0.f;
#pragma unroll
    for (int ww = 0; ww < 4; ww++) { pd += pstat[ww][t][0]; ws += pstat[ww][t][1]; }
    float nsim = nsimb[t];
    int es = eidx[t][0], ed = eidx[t][1];
    float u0 = softplusf(craw[0]), u1 = softplusf(craw[1]), u2 = softplusf(craw[2]);
    float usum = u0 + u1 + u2;
    float c0 = u0 / usum, c1 = u1 / usum, c2 = u2 / usum;
    float sc = sscale[0], sh = sshift[0];
    int sidx = s0 + t;
    out[3 * sidx + 0] = c0 * (pd + bp[0]);
    out[3 * sidx + 1] = c1 * (sc * (nsim + sh));
    out[3 * sidx + 2] = c2 * (sc * (cong[es] + cong[ed] + sh));
    out[3 * ESn + sidx] = fmaxf(ws + nsim * Ww[128] + bw[0], 0.f);
    if (blockIdx.x == 0 && t == 0) {
      out[4 * ESn + 0] = c0; out[4 * ESn + 1] = c1; out[4 * ESn + 2] = c2;
    }
  }
}

} // namespace

extern "C" void kernel_launch(void* const* d_in, const int* in_sizes, int n_in,
                              void* d_out, int out_size, void* d_ws, size_t ws_size,
                              hipStream_t stream) {
  (void)in_sizes; (void)n_in; (void)out_size; (void)ws_size;
  const float* nodes  = (const float*)d_in[0];
  const float* nbrs   = (const float*)d_in[1];
  const int* sup_src  = (const int*)d_in[2];
  const int* sup_dst  = (const int*)d_in[3];
  const int* msg_src  = (const int*)d_in[4];
  const int* msg_dst  = (const int*)d_in[5];
  // d_in[6] message_edgestr: dead
  const float* W0  = (const float*)d_in[7];
  const float* b0  = (const float*)d_in[8];
  const float* g0  = (const float*)d_in[9];
  const float* be0 = (const float*)d_in[10];
  const float* W1  = (const float*)d_in[11];
  const float* b1  = (const float*)d_in[12];
  const float* g1  = (const float*)d_in[13];
  const float* be1 = (const float*)d_in[14];
  const float* Wp  = (const float*)d_in[15];
  const float* bp  = (const float*)d_in[16];
  const float* Ww  = (const float*)d_in[17];
  const float* bw  = (const float*)d_in[18];
  const float* sscale = (const float*)d_in[19];
  const float* sshift = (const float*)d_in[20];
  const float* craw   = (const float*)d_in[21];
  // d_in[22..27] mm_*: dead
  float* out = (float*)d_out;

  char* p = (char*)d_ws;
  auto take = [&](size_t bytes) -> char* {
    char* r = p; p += (bytes + 255) & ~(size_t)255; return r;
  };
  ushort* w0t     = (ushort*)take((size_t)256 * 256 * 2);
  ushort* w1t     = (ushort*)take((size_t)128 * 256 * 2);
  char*   qnodes  = take((size_t)NN * CC);
  char*   qunit   = take((size_t)NN * CC);
  char*   qnbrs   = take((size_t)NN * CC);
  float*  nscale  = (float*)take((size_t)NN * 4);
  float*  nbscale = (float*)take((size_t)NN * 4);
  int*    pidx    = (int*)take((size_t)NN * 4);
  float*  den     = (float*)take((size_t)NN * 4);
  float*  num     = (float*)take((size_t)NN * 4);
  float*  cnt     = (float*)take((size_t)NN * 4);
  float*  cong    = (float*)take((size_t)NN * 4);

  k_init<<<(NN + 255) / 256, 256, 0, stream>>>(pidx, den, num, cnt);
  k_cvtq<<<(2 * NN + 15) / 16, 256, 0, stream>>>(nodes, nbrs, qnodes, qunit, qnbrs,
                                                 nscale, nbscale);
  k_prep<<<96, 256, 0, stream>>>(W0, W1, w0t, w1t);
  k_partner<<<(2 * ESn + 255) / 256, 256, 0, stream>>>(sup_src, sup_dst, pidx);
  k_cos8<<<EMn / 32, 256, 0, stream>>>(qunit, sup_src, sup_dst, msg_src, msg_dst,
                                       pidx, den, num, cnt);
  k_cong<<<(NN + 255) / 256, 256, 0, stream>>>(den, num, cnt, cong);
  k_mlp<<<ESn / 64, 256, 0, stream>>>(qnodes, nscale, qnbrs, nbscale,
                                      sup_src, sup_dst, cong,
                                      w0t, w1t, b0, g0, be0, b1, g1, be1,
                                      Wp, bp, Ww, bw, sscale, sshift, craw, out);
}